// Round 13
// baseline (7816.360 us; speedup 1.0000x reference)
//
#include <hip/hip_runtime.h>
#include <math.h>
#include <stdint.h>

#define D     512
#define DFF   2048
#define BB    8
#define NH    8
#define HD    64
#define NV    32000
#define NL    4
#define TMAX  17
#define KC    64
#define STEPS 16
#define KTOP  50
#define PAD_ID 0
#define BOS_ID 2
#define EOS_ID 3
#define SCOPE __HIP_MEMORY_SCOPE_AGENT

__device__ __forceinline__ float ld1(const float* p) {
  return __hip_atomic_load(p, __ATOMIC_RELAXED, SCOPE);
}
__device__ __forceinline__ void st1(float* p, float v) {
  __hip_atomic_store(p, v, __ATOMIC_RELAXED, SCOPE);
}
__device__ __forceinline__ float2 ld2(const float* p) {
  union { double d; float2 f; } u;
  u.d = __hip_atomic_load((const double*)p, __ATOMIC_RELAXED, SCOPE);
  return u.f;
}
__device__ __forceinline__ unsigned ldu(const unsigned* p) {
  return __hip_atomic_load(p, __ATOMIC_RELAXED, SCOPE);
}

__device__ __forceinline__ void tf2x32(unsigned k0, unsigned k1, unsigned x0, unsigned x1,
                                       unsigned& o0, unsigned& o1)
{
  unsigned ks2 = k0 ^ k1 ^ 0x1BD11BDAu;
#define TFR(r) { x0 += x1; x1 = (x1 << (r)) | (x1 >> (32 - (r))); x1 ^= x0; }
  x0 += k0; x1 += k1;
  TFR(13) TFR(15) TFR(26) TFR(6)
  x0 += k1;  x1 += ks2 + 1u;
  TFR(17) TFR(29) TFR(16) TFR(24)
  x0 += ks2; x1 += k0 + 2u;
  TFR(13) TFR(15) TFR(26) TFR(6)
  x0 += k0;  x1 += k1 + 3u;
  TFR(17) TFR(29) TFR(16) TFR(24)
  x0 += k1;  x1 += ks2 + 4u;
  TFR(13) TFR(15) TFR(26) TFR(6)
  o0 = x0 + ks2; o1 = x1 + k0 + 5u;
#undef TFR
}

__device__ __forceinline__ float wredf(float v) {
  for (int o = 32; o; o >>= 1) v += __shfl_xor(v, o, 64);
  return v;
}
__device__ __forceinline__ float wredmaxf(float v) {
  for (int o = 32; o; o >>= 1) v = fmaxf(v, __shfl_xor(v, o, 64));
  return v;
}
__device__ __forceinline__ unsigned monok(float f) {
  unsigned u = __float_as_uint(f);
  return (u & 0x80000000u) ? ~u : (u | 0x80000000u);
}

#define DOT8(a0,a1,x0,x1) (a0.x*x0.x + a0.y*x0.y + a0.z*x0.z + a0.w*x0.w + \
                           a1.x*x1.x + a1.y*x1.y + a1.z*x1.z + a1.w*x1.w)

__global__ void init_k(int* toks, unsigned* bars)
{
  int i = threadIdx.x;
  if (i < BB) toks[i * TMAX] = BOS_ID;
  for (int k = i; k < 2048; k += 256) bars[k] = 0u;
}

__global__ void cross_kv_k(const float* __restrict__ state, const float* __restrict__ qkvw,
                           const float* __restrict__ qkvb, float* __restrict__ cK,
                           float* __restrict__ cV)
{
  int gx = blockIdx.x, b = blockIdx.y, tid = threadIdx.x;
  int jblk = gx & 31, kpos = (gx >> 5) & 63, l = gx >> 11;
  int w = tid >> 6, lane = tid & 63;
  __shared__ __align__(16) float xsh[D];
  xsh[tid] = state[((size_t)b * KC + kpos) * D + tid];
  xsh[tid + 256] = state[((size_t)b * KC + kpos) * D + tid + 256];
  __syncthreads();
  for (int i = 0; i < 8; i++) {
    int j = jblk * 32 + w * 8 + i;
    int row = D + j;
    const float4* wr = (const float4*)(qkvw + (((size_t)l * 2 + 1) * (3 * D) + row) * D);
    const float4* x4 = (const float4*)xsh;
    float acc = 0.f;
    for (int e = lane; e < 128; e += 64) {
      float4 a = wr[e], xx = x4[e];
      acc += a.x * xx.x + a.y * xx.y + a.z * xx.z + a.w * xx.w;
    }
    acc = wredf(acc);
    if (lane == 0) {
      float v = acc + qkvb[((size_t)l * 2 + 1) * (3 * D) + row];
      float* dst = (j < D) ? cK : cV;
      int jj = (j < D) ? j : j - D;
      dst[(((size_t)l * BB + b) * KC + kpos) * D + jj] = v;
    }
  }
}

// ---- persistent decode: 64 blocks = (batch b = bid&7, head h = bid>>3) ----
extern "C" __global__ void __launch_bounds__(512, 2)
decode_k(const float* __restrict__ emb, const float* __restrict__ qkv_w,
         const float* __restrict__ qkv_b, const float* __restrict__ out_w,
         const float* __restrict__ out_b, const float* __restrict__ f_w1,
         const float* __restrict__ f_b1, const float* __restrict__ f_w2,
         const float* __restrict__ f_b2, const float* __restrict__ lng,
         const float* __restrict__ lnb,
         const float* __restrict__ cK, const float* __restrict__ cV,
         float* Kc, float* Vc, float* xt2p, float* xt3p, float* xt4p,
         float* xcur, float* lg, unsigned* bars, int* toks)
{
  const int tid = threadIdx.x, bid = blockIdx.x;
  const int b = bid & 7, h = bid >> 3;
  const int w = tid >> 6, lane = tid & 63;
  unsigned gp = 0, glp = 0;
  int finished = 0;

  __shared__ __align__(16) unsigned char smem[65280];
  float* F = (float*)smem;
  float* sX1n = F;            // 512  (x input, post-LN; residual source)
  float* sXn  = F + 512;      // 512  (x2 / x3)
  float* sQh  = F + 1024;     // 64
  float* sKt  = F + 1088;     // 64
  float* sVt  = F + 1152;     // 64
  float* sS   = F + 1216;     // 64
  float* sSP  = F + 1280;     // 64
  float* sPart= F + 1344;     // 512
  float* sAO  = F + 1856;     // 64
  float* sH   = F + 1920;     // 256 (ends 2176)
  float* sL   = F;            // logits phase: [8][512] (alias, ends 4096)
  unsigned short* key16 = (unsigned short*)smem;       // sample (64000B)
  unsigned* histA = (unsigned*)(smem + 64000);
  unsigned* sKeys = (unsigned*)(smem + 64000);
  unsigned* sMeta = (unsigned*)(smem + 65024);
  float*    sWin  = (float*)(smem + 65056);            // 8
  int*      sWix  = (int*)(smem + 65088);              // 8
  float*    sRed  = (float*)(smem + 65152);            // 8 (safe in all phases)

  const float SQD = (float)22.627416997969522;
  const float PEC = (float)(9.210340371976184 / 512.0);
  const float SQRT2 = (float)1.4142135623730951;

  auto gbarg = [&]() {   // group barrier: 8 blocks of batch b
    asm volatile("s_waitcnt vmcnt(0)" ::: "memory");
    __syncthreads();
    ++gp;
    if (tid == 0) {
      unsigned* c = bars + b * 32;
      __hip_atomic_fetch_add(c, 1u, __ATOMIC_RELAXED, SCOPE);
      unsigned tgt = gp * 8u;
      while (ldu(c) < tgt) __builtin_amdgcn_s_sleep(1);
    }
    asm volatile("" ::: "memory");
    __syncthreads();
  };
  auto gbarall = [&]() { // global barrier: 64 blocks
    asm volatile("s_waitcnt vmcnt(0)" ::: "memory");
    __syncthreads();
    ++glp;
    if (tid == 0) {
      unsigned* c = bars + 512;
      __hip_atomic_fetch_add(c, 1u, __ATOMIC_RELAXED, SCOPE);
      unsigned tgt = glp * 64u;
      while (ldu(c) < tgt) __builtin_amdgcn_s_sleep(1);
    }
    asm volatile("" ::: "memory");
    __syncthreads();
  };

  // block-wide LN of per-thread value a (512 threads = 512 elems) -> dst[tid]
  auto lnvec = [&](float a, const float* ga, const float* be, float* dst) {
    float s = wredf(a);
    if (lane == 0) sRed[w] = s;
    __syncthreads();
    float mu = (sRed[0]+sRed[1]+sRed[2]+sRed[3]+sRed[4]+sRed[5]+sRed[6]+sRed[7]) * (1.0f/512.0f);
    __syncthreads();
    float d0 = a - mu;
    float q = wredf(d0 * d0);
    if (lane == 0) sRed[w] = q;
    __syncthreads();
    float sd = sqrtf((sRed[0]+sRed[1]+sRed[2]+sRed[3]+sRed[4]+sRed[5]+sRed[6]+sRed[7]) * (1.0f/512.0f) + 1e-5f);
    dst[tid] = d0 / sd * ga[tid] + be[tid];
    __syncthreads();
  };

  // ---- initial: embed BOS (blocks 0..7 = batch bid, h==0) ----
  if (bid < BB) {
    float pe = (tid & 1) ? 1.0f : 0.0f;
    st1(&xcur[bid * D + tid], emb[(size_t)BOS_ID * D + tid] * SQD + pe);
  }
  gbarg();

  for (int t = 0; t < STEPS; ++t) {
    const int T = t + 1;
    for (int l = 0; l < NL; ++l) {
      const float* wqkv0 = qkv_w + ((size_t)l * 2 + 0) * (3 * D) * D;
      const float* bqkv0 = qkv_b + ((size_t)l * 2 + 0) * (3 * D);
      const float* wqkv1 = qkv_w + ((size_t)l * 2 + 1) * (3 * D) * D;
      const float* bqkv1 = qkv_b + ((size_t)l * 2 + 1) * (3 * D);
      const float* wo0 = out_w + ((size_t)l * 2 + 0) * D * D;
      const float* bo0 = out_b + ((size_t)l * 2 + 0) * D;
      const float* wo1 = out_w + ((size_t)l * 2 + 1) * D * D;
      const float* bo1 = out_b + ((size_t)l * 2 + 1) * D;
      const size_t kvbase = ((size_t)(b * NH + h) * NL + l) * TMAX * HD;

      // ================= P1: x1n + QKV(head) + self-attn + Wo0-cols =========
      if (l == 0) {
        sX1n[tid] = ld1(&xcur[b * D + tid]);
        __syncthreads();
      } else {
        float a = 0.f;
#pragma unroll
        for (int s2 = 0; s2 < 8; ++s2) a += ld1(&xt4p[((size_t)b * 8 + s2) * D + tid]);
        lnvec(a, lng + ((size_t)(l - 1) * 3 + 2) * D, lnb + ((size_t)(l - 1) * 3 + 2) * D, sX1n);
      }
      {
        const float4* x4 = (const float4*)sX1n;
        float4 x0 = x4[lane], x1v = x4[lane + 64];
        for (int set = 0; set < 3; ++set) {
          int rowbase = set * 512 + h * 64 + w * 8;
          for (int pass = 0; pass < 2; ++pass) {
            float4 wa[4], wb2[4];
#pragma unroll
            for (int r = 0; r < 4; ++r) {
              const float4* w4 = (const float4*)(wqkv0 + (size_t)(rowbase + pass * 4 + r) * D);
              wa[r] = w4[lane]; wb2[r] = w4[lane + 64];
            }
            float a4[4];
#pragma unroll
            for (int r = 0; r < 4; ++r) a4[r] = DOT8(wa[r], wb2[r], x0, x1v);
#pragma unroll
            for (int o = 32; o; o >>= 1) {
#pragma unroll
              for (int r = 0; r < 4; ++r) a4[r] += __shfl_xor(a4[r], o, 64);
            }
            if (lane == 0) {
#pragma unroll
              for (int r = 0; r < 4; ++r) {
                int jj = w * 8 + pass * 4 + r;          // 0..63 head-local
                int row = rowbase + pass * 4 + r;
                float v = a4[r] + bqkv0[row];
                if (set == 0)      sQh[jj] = v;
                else if (set == 1) { st1(&Kc[kvbase + (size_t)t * HD + jj], v); sKt[jj] = v; }
                else               { st1(&Vc[kvbase + (size_t)t * HD + jj], v); sVt[jj] = v; }
              }
            }
          }
        }
      }
      __syncthreads();
      for (int k = w; k < T; k += 8) {
        float kv = (k == t) ? sKt[lane] : Kc[kvbase + (size_t)k * HD + lane];
        float sc = wredf(sQh[lane] * kv);
        if (lane == 0) sS[k] = sc * 0.125f;
      }
      __syncthreads();
      if (w == 0) {
        float v = (lane < T) ? sS[lane] : -INFINITY;
        float m = wredmaxf(v);
        float p = (lane < T) ? expf(v - m) : 0.f;
        float den = wredf(p);
        if (lane < T) sSP[lane] = p / den;
      }
      __syncthreads();
      {
        float acc = 0.f;
        for (int k = w; k < T; k += 8) {
          float vv = (k == t) ? sVt[lane] : Vc[kvbase + (size_t)k * HD + lane];
          acc += sSP[k] * vv;
        }
        sPart[w * 64 + lane] = acc;
      }
      __syncthreads();
      if (tid < 64) {
        float a = 0.f;
#pragma unroll
        for (int i = 0; i < 8; ++i) a += sPart[i * 64 + tid];
        sAO[tid] = a;
      }
      __syncthreads();
      {
        int j = tid;
        const float4* wr4 = (const float4*)(wo0 + (size_t)j * D + h * HD);
        float acc = 0.f;
#pragma unroll
        for (int e = 0; e < 16; ++e) {
          float4 aw = wr4[e];
          acc += aw.x * sAO[e*4] + aw.y * sAO[e*4+1] + aw.z * sAO[e*4+2] + aw.w * sAO[e*4+3];
        }
        if (h == 0) acc += bo0[j] + sX1n[j];
        st1(&xt2p[((size_t)b * 8 + h) * D + j], acc);
      }
      gbarg();

      // ================= P2: x2=LN(Σxt2p) + crossQ(head) + cross-attn + Wo1-cols
      {
        float a = 0.f;
#pragma unroll
        for (int s2 = 0; s2 < 8; ++s2) a += ld1(&xt2p[((size_t)b * 8 + s2) * D + tid]);
        lnvec(a, lng + ((size_t)l * 3 + 0) * D, lnb + ((size_t)l * 3 + 0) * D, sXn);
      }
      {
        const float4* x4 = (const float4*)sXn;
        float4 x0 = x4[lane], x1v = x4[lane + 64];
        for (int pass = 0; pass < 2; ++pass) {
          float4 wa[4], wb2[4];
#pragma unroll
          for (int r = 0; r < 4; ++r) {
            const float4* w4 = (const float4*)(wqkv1 + (size_t)(h * 64 + w * 8 + pass * 4 + r) * D);
            wa[r] = w4[lane]; wb2[r] = w4[lane + 64];
          }
          float a4[4];
#pragma unroll
          for (int r = 0; r < 4; ++r) a4[r] = DOT8(wa[r], wb2[r], x0, x1v);
#pragma unroll
          for (int o = 32; o; o >>= 1) {
#pragma unroll
            for (int r = 0; r < 4; ++r) a4[r] += __shfl_xor(a4[r], o, 64);
          }
          if (lane == 0) {
#pragma unroll
            for (int r = 0; r < 4; ++r) {
              int jj = w * 8 + pass * 4 + r;
              sQh[jj] = a4[r] + bqkv1[h * 64 + jj];
            }
          }
        }
      }
      __syncthreads();
      {
        size_t cbase = (((size_t)l * BB + b) * KC) * D + h * HD;
        for (int k = w; k < KC; k += 8) {
          float sc = wredf(sQh[lane] * cK[cbase + (size_t)k * D + lane]);
          if (lane == 0) sS[k] = sc * 0.125f;
        }
        __syncthreads();
        if (w == 0) {
          float v = sS[lane];
          float m = wredmaxf(v);
          float p = expf(v - m);
          float den = wredf(p);
          sSP[lane] = p / den;
        }
        __syncthreads();
        float acc = 0.f;
        for (int k = w; k < KC; k += 8) acc += sSP[k] * cV[cbase + (size_t)k * D + lane];
        sPart[w * 64 + lane] = acc;
      }
      __syncthreads();
      if (tid < 64) {
        float a = 0.f;
#pragma unroll
        for (int i = 0; i < 8; ++i) a += sPart[i * 64 + tid];
        sAO[tid] = a;
      }
      __syncthreads();
      {
        int j = tid;
        const float4* wr4 = (const float4*)(wo1 + (size_t)j * D + h * HD);
        float acc = 0.f;
#pragma unroll
        for (int e = 0; e < 16; ++e) {
          float4 aw = wr4[e];
          acc += aw.x * sAO[e*4] + aw.y * sAO[e*4+1] + aw.z * sAO[e*4+2] + aw.w * sAO[e*4+3];
        }
        if (h == 0) acc += bo1[j] + sXn[j];
        st1(&xt3p[((size_t)b * 8 + h) * D + j], acc);
      }
      gbarg();

      // ================= P3: x3=LN(Σxt3p) + FFN1 rows + FFN2-cols ===========
      {
        float a = 0.f;
#pragma unroll
        for (int s2 = 0; s2 < 8; ++s2) a += ld1(&xt3p[((size_t)b * 8 + s2) * D + tid]);
        lnvec(a, lng + ((size_t)l * 3 + 1) * D, lnb + ((size_t)l * 3 + 1) * D, sXn);
      }
      {
        const float4* x4 = (const float4*)sXn;
        float4 x0 = x4[lane], x1v = x4[lane + 64];
        for (int pass = 0; pass < 8; ++pass) {
          int rl0 = w * 32 + pass * 4;                  // head-local row 0..255
          float4 wa[4], wb2[4];
#pragma unroll
          for (int r = 0; r < 4; ++r) {
            const float4* w4 = (const float4*)(f_w1 + (size_t)l * DFF * D + (size_t)(h * 256 + rl0 + r) * D);
            wa[r] = w4[lane]; wb2[r] = w4[lane + 64];
          }
          float a4[4];
#pragma unroll
          for (int r = 0; r < 4; ++r) a4[r] = DOT8(wa[r], wb2[r], x0, x1v);
#pragma unroll
          for (int o = 32; o; o >>= 1) {
#pragma unroll
            for (int r = 0; r < 4; ++r) a4[r] += __shfl_xor(a4[r], o, 64);
          }
          if (lane == 0) {
#pragma unroll
            for (int r = 0; r < 4; ++r) {
              float v = a4[r] + f_b1[(size_t)l * DFF + h * 256 + rl0 + r];
              v = v * (erff(v / SQRT2) + 1.0f) / 2.0f;
              sH[rl0 + r] = v;
            }
          }
        }
      }
      __syncthreads();
      {
        int j = tid;
        const float4* wr4 = (const float4*)(f_w2 + (size_t)l * D * DFF + (size_t)j * DFF + h * 256);
        float acc = 0.f;
#pragma unroll 8
        for (int e = 0; e < 64; ++e) {
          float4 aw = wr4[e];
          acc += aw.x * sH[e*4] + aw.y * sH[e*4+1] + aw.z * sH[e*4+2] + aw.w * sH[e*4+3];
        }
        if (h == 0) acc += f_b2[(size_t)l * D + j] + sXn[j];
        st1(&xt4p[((size_t)b * 8 + h) * D + j], acc);
      }
      if (l < NL - 1) gbarg(); else gbarall();
    } // l

    // ================= logits: all 64 blocks, 500 vocab cols each ===========
    {
      float accb[8];
#pragma unroll
      for (int bb = 0; bb < 8; ++bb) {
        float a = 0.f;
#pragma unroll
        for (int s2 = 0; s2 < 8; ++s2) a += ld1(&xt4p[((size_t)bb * 8 + s2) * D + tid]);
        accb[bb] = a;
      }
      const float* ga = lng + 11 * D;
      const float* be = lnb + 11 * D;
#pragma unroll
      for (int bb = 0; bb < 8; ++bb)
        lnvec(accb[bb], ga, be, sL + bb * 512);
    }
    for (int i = w; i < 500; i += 8) {
      int v = i * 64 + bid;
      const float4* er = (const float4*)(emb + (size_t)v * D);
      float4 e0 = er[lane], e1 = er[lane + 64];
      float acc[8];
#pragma unroll
      for (int bb = 0; bb < 8; bb++) {
        const float4* x4 = (const float4*)(sL + bb * 512);
        float4 x0 = x4[lane], x1v = x4[lane + 64];
        acc[bb] = DOT8(e0, e1, x0, x1v);
      }
#pragma unroll
      for (int o = 32; o; o >>= 1) {
#pragma unroll
        for (int bb = 0; bb < 8; bb++) acc[bb] += __shfl_xor(acc[bb], o, 64);
      }
      if (lane == 0) {
#pragma unroll
        for (int bb = 0; bb < 8; bb++) st1(&lg[(size_t)bb * NV + v], acc[bb]);
      }
    }
    gbarall();

    // ================= sample (blocks 0..7, block b = batch b) ==============
    if (bid < BB) {
      if (tid < 256) histA[tid] = 0u;
      __syncthreads();
      for (int v2 = tid; v2 < NV / 2; v2 += 512) {
        float2 f = ld2(&lg[(size_t)b * NV + 2 * v2]);
        unsigned u0 = monok(f.x), u1 = monok(f.y);
        key16[2 * v2] = (unsigned short)(u0 >> 16);
        key16[2 * v2 + 1] = (unsigned short)(u1 >> 16);
        atomicAdd(&histA[u0 >> 24], 1u);
        atomicAdd(&histA[u1 >> 24], 1u);
      }
      __syncthreads();
      if (tid == 0) {
        unsigned k = KTOP, cum = 0;
        for (int bin = 255; bin >= 0; bin--) {
          cum += histA[bin];
          if (cum >= k) { sMeta[0] = (unsigned)bin; sMeta[1] = k - (cum - histA[bin]); break; }
        }
      }
      __syncthreads();
      unsigned selHi = sMeta[0], rem1 = sMeta[1];
      if (tid < 256) histA[tid] = 0u;
      __syncthreads();
      for (int v = tid; v < NV; v += 512) {
        unsigned k16 = key16[v];
        if ((k16 >> 8) == selHi) atomicAdd(&histA[k16 & 255u], 1u);
      }
      __syncthreads();
      if (tid == 0) {
        unsigned k = rem1, cum = 0;
        for (int bin = 255; bin >= 0; bin--) {
          cum += histA[bin];
          if (cum >= k) { sMeta[2] = (selHi << 8) | (unsigned)bin; sMeta[1] = k - (cum - histA[bin]); break; }
        }
        sMeta[3] = 0u;
      }
      __syncthreads();
      unsigned P16 = sMeta[2], rem2 = sMeta[1];
      for (int v = tid; v < NV; v += 512) {
        if (key16[v] == (unsigned short)P16) {
          unsigned i = atomicAdd(&sMeta[3], 1u);
          if (i < 256) sKeys[i] = monok(ld1(&lg[(size_t)b * NV + v]));
        }
      }
      __syncthreads();
      if (tid == 0) {
        unsigned n = sMeta[3]; if (n > 256) n = 256;
        unsigned thr = 0;
        for (unsigned it = 0; it < rem2; ++it) {
          unsigned bestk = 0; int bj = 0;
          for (unsigned jx = 0; jx < n; jx++)
            if (sKeys[jx] > bestk) { bestk = sKeys[jx]; bj = (int)jx; }
          thr = bestk;
          sKeys[bj] = 0u;
        }
        sMeta[5] = (thr & 0x80000000u) ? (thr ^ 0x80000000u) : ~thr;
      }
      __syncthreads();
      float th = __uint_as_float(sMeta[5]);
      unsigned k0, k1;
      tf2x32(0u, 1u, 0u, (unsigned)t, k0, k1);
      float best = -INFINITY; int bi = NV;
      for (int v = tid; v < NV; v += 512) {
        if (key16[v] >= (unsigned short)P16) {
          float lo = ld1(&lg[(size_t)b * NV + v]);
          if (lo >= th) {
            unsigned o0, o1;
            tf2x32(k0, k1, 0u, (unsigned)(b * NV + v), o0, o1);
            unsigned bits = o0 ^ o1;
            unsigned ub = (bits >> 9) | 0x3f800000u;
            float fu = __uint_as_float(ub) - 1.0f;
            const float TINY = 1.17549435e-38f;
            float u = fu * (1.0f - TINY) + TINY;
            u = fmaxf(TINY, u);
            float gmb = -logf(-logf(u));
            float s = lo + gmb;
            if (s > best || (s == best && v < bi)) { best = s; bi = v; }
          }
        }
      }
      for (int o = 32; o; o >>= 1) {
        float ob = __shfl_xor(best, o, 64); int ox = __shfl_xor(bi, o, 64);
        if (ob > best || (ob == best && ox < bi)) { best = ob; bi = ox; }
      }
      if (lane == 0) { sWin[w] = best; sWix[w] = bi; }
      __syncthreads();
      if (tid == 0) {
        float bb2 = sWin[0]; int bx = sWix[0];
        for (int i2 = 1; i2 < 8; i2++) {
          if (sWin[i2] > bb2 || (sWin[i2] == bb2 && sWix[i2] < bx)) { bb2 = sWin[i2]; bx = sWix[i2]; }
        }
        int tok = bx;
        if (finished) tok = PAD_ID;
        toks[b * TMAX + t + 1] = tok;
        if (tok == EOS_ID) finished = 1;
        sMeta[4] = (unsigned)tok;
      }
      __syncthreads();
      {
        int tok = (int)sMeta[4];
        float omega = expf(-(float)(tid & ~1) * PEC);
        float val = (float)(t + 1) * omega;
        float pe = (tid & 1) ? cosf(val) : sinf(val);
        st1(&xcur[b * D + tid], emb[(size_t)tok * D + tid] * SQD + pe);
      }
    }
    gbarg();
  } // t
}

// ---------------- host orchestration ----------------
extern "C" void kernel_launch(void* const* d_in, const int* in_sizes, int n_in,
                              void* d_out, int out_size, void* d_ws, size_t ws_size,
                              hipStream_t stream)
{
  const float* state = (const float*)d_in[0];
  const float* emb   = (const float*)d_in[1];
  const float* qkv_w = (const float*)d_in[2];
  const float* qkv_b = (const float*)d_in[3];
  const float* out_w = (const float*)d_in[4];
  const float* out_b = (const float*)d_in[5];
  const float* f_w1  = (const float*)d_in[6];
  const float* f_b1  = (const float*)d_in[7];
  const float* f_w2  = (const float*)d_in[8];
  const float* f_b2  = (const float*)d_in[9];
  const float* lng   = (const float*)d_in[10];
  const float* lnb   = (const float*)d_in[11];

  float* ws = (float*)d_ws;
  float* cK   = ws;                                       // 4*8*64*512
  float* cV   = cK + (size_t)NL * BB * KC * D;
  float* Kc   = cV + (size_t)NL * BB * KC * D;            // 8*8*4*17*64
  float* Vc   = Kc + (size_t)BB * NH * NL * TMAX * HD;
  float* xt2p = Vc + (size_t)BB * NH * NL * TMAX * HD;    // 8*8*512
  float* xt3p = xt2p + (size_t)BB * 8 * D;
  float* xt4p = xt3p + (size_t)BB * 8 * D;
  float* xcur = xt4p + (size_t)BB * 8 * D;                // 8*512
  float* lg   = xcur + BB * D;                            // 8*32000
  unsigned* bars = (unsigned*)(lg + (size_t)BB * NV);     // 2048 u32

  int* toks = (int*)d_out;

  init_k<<<1, 256, 0, stream>>>(toks, bars);
  cross_kv_k<<<dim3(NL * KC * 32, BB), 256, 0, stream>>>(state, qkv_w, qkv_b, cK, cV);
  decode_k<<<64, 512, 0, stream>>>(emb, qkv_w, qkv_b, out_w, out_b,
                                   f_w1, f_b1, f_w2, f_b2, lng, lnb,
                                   cK, cV, Kc, Vc, xt2p, xt3p, xt4p,
                                   xcur, lg, bars, toks);
}

// Round 14
// 4921.954 us; speedup vs baseline: 1.5881x; 1.5881x over previous
//
#include <hip/hip_runtime.h>
#include <math.h>
#include <stdint.h>

#define D     512
#define DFF   2048
#define BB    8
#define NB    2              // batches per group
#define NG    4              // groups (XCD pairs)
#define NH    8
#define HD    64
#define NV    32000
#define NL    4
#define TMAX  17
#define KC    64
#define STEPS 16
#define KTOP  50
#define PAD_ID 0
#define BOS_ID 2
#define EOS_ID 3
#define SCOPE __HIP_MEMORY_SCOPE_AGENT

// ---------------- coherent (cache-bypassing) access -------------------------
__device__ __forceinline__ float ld1(const float* p) {
  return __hip_atomic_load(p, __ATOMIC_RELAXED, SCOPE);
}
__device__ __forceinline__ void st1(float* p, float v) {
  __hip_atomic_store(p, v, __ATOMIC_RELAXED, SCOPE);
}
__device__ __forceinline__ float2 ld2(const float* p) {
  union { double d; float2 f; } u;
  u.d = __hip_atomic_load((const double*)p, __ATOMIC_RELAXED, SCOPE);
  return u.f;
}
__device__ __forceinline__ unsigned ldu(const unsigned* p) {
  return __hip_atomic_load(p, __ATOMIC_RELAXED, SCOPE);
}

// ---------------- threefry2x32 (matches jax lowering exactly) ----------------
__device__ __forceinline__ void tf2x32(unsigned k0, unsigned k1, unsigned x0, unsigned x1,
                                       unsigned& o0, unsigned& o1)
{
  unsigned ks2 = k0 ^ k1 ^ 0x1BD11BDAu;
#define TFR(r) { x0 += x1; x1 = (x1 << (r)) | (x1 >> (32 - (r))); x1 ^= x0; }
  x0 += k0; x1 += k1;
  TFR(13) TFR(15) TFR(26) TFR(6)
  x0 += k1;  x1 += ks2 + 1u;
  TFR(17) TFR(29) TFR(16) TFR(24)
  x0 += ks2; x1 += k0 + 2u;
  TFR(13) TFR(15) TFR(26) TFR(6)
  x0 += k0;  x1 += k1 + 3u;
  TFR(17) TFR(29) TFR(16) TFR(24)
  x0 += k1;  x1 += ks2 + 4u;
  TFR(13) TFR(15) TFR(26) TFR(6)
  o0 = x0 + ks2; o1 = x1 + k0 + 5u;
#undef TFR
}

__device__ __forceinline__ float wredf(float v) {
  for (int o = 32; o; o >>= 1) v += __shfl_xor(v, o, 64);
  return v;
}
__device__ __forceinline__ float wredmaxf(float v) {
  for (int o = 32; o; o >>= 1) v = fmaxf(v, __shfl_xor(v, o, 64));
  return v;
}
__device__ __forceinline__ unsigned monok(float f) {
  unsigned u = __float_as_uint(f);
  return (u & 0x80000000u) ? ~u : (u | 0x80000000u);
}

#define DOT8(a0,a1,x0,x1) (a0.x*x0.x + a0.y*x0.y + a0.z*x0.z + a0.w*x0.w + \
                           a1.x*x1.x + a1.y*x1.y + a1.z*x1.z + a1.w*x1.w)

// ---------------- init: BOS tokens + barrier state --------------------------
__global__ void init_k(int* toks, unsigned* bars)
{
  int i = threadIdx.x;
  if (i < BB) toks[i * TMAX] = BOS_ID;
  for (int k = i; k < 2048; k += 256) bars[k] = 0u;
}

// ---------------- cross-attention K/V precompute (one-time) -----------------
__global__ void cross_kv_k(const float* __restrict__ state, const float* __restrict__ qkvw,
                           const float* __restrict__ qkvb, float* __restrict__ cK,
                           float* __restrict__ cV)
{
  int gx = blockIdx.x, b = blockIdx.y, tid = threadIdx.x;
  int jblk = gx & 31, kpos = (gx >> 5) & 63, l = gx >> 11;
  int w = tid >> 6, lane = tid & 63;
  __shared__ __align__(16) float xsh[D];
  xsh[tid] = state[((size_t)b * KC + kpos) * D + tid];
  xsh[tid + 256] = state[((size_t)b * KC + kpos) * D + tid + 256];
  __syncthreads();
  for (int i = 0; i < 8; i++) {
    int j = jblk * 32 + w * 8 + i;
    int row = D + j;
    const float4* wr = (const float4*)(qkvw + (((size_t)l * 2 + 1) * (3 * D) + row) * D);
    const float4* x4 = (const float4*)xsh;
    float acc = 0.f;
    for (int e = lane; e < 128; e += 64) {
      float4 a = wr[e], xx = x4[e];
      acc += a.x * xx.x + a.y * xx.y + a.z * xx.z + a.w * xx.w;
    }
    acc = wredf(acc);
    if (lane == 0) {
      float v = acc + qkvb[((size_t)l * 2 + 1) * (3 * D) + row];
      float* dst = (j < D) ? cK : cV;
      int jj = (j < D) ? j : j - D;
      dst[(((size_t)l * BB + b) * KC + kpos) * D + jj] = v;
    }
  }
}

// ---------------- persistent grouped decode kernel --------------------------
extern "C" __global__ void __launch_bounds__(512, 2)
decode_k(const float* __restrict__ emb, const float* __restrict__ qkv_w,
         const float* __restrict__ qkv_b, const float* __restrict__ out_w,
         const float* __restrict__ out_b, const float* __restrict__ f_w1,
         const float* __restrict__ f_b1, const float* __restrict__ f_w2,
         const float* __restrict__ f_b2, const float* __restrict__ lng,
         const float* __restrict__ lnb,
         const float* __restrict__ cK, const float* __restrict__ cV,
         float* Kc, float* Vc, float* qS, float* q2S,
         float* xt2, float* xt3, float* xt4, float* hB,
         float* xcur, float* lg, unsigned* bars, int* toks)
{
  const int tid = threadIdx.x, bid = blockIdx.x;
  const int xcd = bid & 7;
  const int g2 = xcd >> 1;                  // group 0..3 (XCD pair, 2 batches)
  const int half = xcd & 1;
  const int hid = bid >> 3;                 // 0..31 per-XCD id
  const int gid = hid * 2 + half;           // 0..63 in-group id
  const int sb = (gid + g2 * 16) & 63;      // skewed row-slot (decorrelate groups)
  const int b0 = g2 * 2, b1 = b0 + 1;
  const int w = tid >> 6, lane = tid & 63;
  const int wb = w >> 2;                    // wave's batch (0/1)
  const int ws = w & 3;                     // wave's row slot (0..3)
  unsigned gp = 0, glp = 0;
  int finished = 0;

  __shared__ __align__(16) unsigned char smem[65280];
  float* F = (float*)smem;
  float* sX1 = F;             // [NB][512]  x1 / x3
  float* sX2 = F + 1024;      // [NB][512]  x2
  float* sQ  = F + 2048;      // [NB][512]
  float* sAO = F + 3072;      // [NB][512]
  float* sS  = F + 4096;      // [NB][544]
  float* sSP = F + 5184;      // [NB][544]
  float* sH  = F + 6272;      // [NB][2048] (ends 10368)
  float* sRed = F + 10368;    // 8
  float* sL  = F;             // alias: logits-phase x rows [8][512]
  unsigned short* key16 = (unsigned short*)smem;         // sample phase (64000B)
  unsigned* histA = (unsigned*)(smem + 64000);
  unsigned* sKeys = (unsigned*)(smem + 64000);
  unsigned* sMeta = (unsigned*)(smem + 65024);
  float*    sWin  = (float*)(smem + 65056);              // 8
  int*      sWix  = (int*)(smem + 65120);                // 8

  const float SQD = (float)22.627416997969522;
  const float PEC = (float)(9.210340371976184 / 512.0);
  const float SQRT2 = (float)1.4142135623730951;

  // group barrier: 64 blocks; arrivals on 4 sub-counters; leader (gid==0)
  // detects and broadcasts to a single gen line polled by everyone else.
  auto gbarg = [&]() {
    asm volatile("s_waitcnt vmcnt(0)" ::: "memory");
    __syncthreads();
    ++gp;
    if (tid == 0) {
      unsigned* c = bars + g2 * 256;
      __hip_atomic_fetch_add(&c[(gid & 3) * 32], 1u, __ATOMIC_RELAXED, SCOPE);
      unsigned tgt = gp * 16u;
      if (gid == 0) {
        for (;;) {
          unsigned s0 = ldu(&c[0]), s1 = ldu(&c[32]), s2 = ldu(&c[64]), s3 = ldu(&c[96]);
          unsigned mn = s0 < s1 ? s0 : s1;
          unsigned mn2 = s2 < s3 ? s2 : s3;
          if ((mn < mn2 ? mn : mn2) >= tgt) break;
          __builtin_amdgcn_s_sleep(1);
        }
        __hip_atomic_store(&c[128], gp, __ATOMIC_RELAXED, SCOPE);
      } else {
        while (ldu(&c[128]) < gp) __builtin_amdgcn_s_sleep(1);
      }
    }
    asm volatile("" ::: "memory");
    __syncthreads();
  };
  // global barrier: 256 blocks; arrivals on 16 sub-counters; leader bid==0
  // broadcasts to one gen line.
  auto gbarall = [&]() {
    asm volatile("s_waitcnt vmcnt(0)" ::: "memory");
    __syncthreads();
    ++glp;
    if (tid == 0) {
      unsigned* c = bars + 1024;
      __hip_atomic_fetch_add(&c[(bid & 15) * 32], 1u, __ATOMIC_RELAXED, SCOPE);
      unsigned tgt = glp * 16u;
      if (bid == 0) {
        for (;;) {
          unsigned mn = 0xFFFFFFFFu;
#pragma unroll
          for (int i = 0; i < 16; i++) { unsigned x = ldu(&c[i * 32]); mn = x < mn ? x : mn; }
          if (mn >= tgt) break;
          __builtin_amdgcn_s_sleep(1);
        }
        __hip_atomic_store(&c[576], glp, __ATOMIC_RELAXED, SCOPE);
      } else {
        while (ldu(&c[576]) < glp) __builtin_amdgcn_s_sleep(1);
      }
    }
    asm volatile("" ::: "memory");
    __syncthreads();
  };

  // two-batch LayerNorm, 512 threads: waves 0-3 batch b0, waves 4-7 batch b1
  auto ln2 = [&](const float* srcbase, const float* gamma, const float* beta, float* dst) {
    int nb = tid >> 8, e = tid & 255;
    const float* sp = srcbase + (size_t)(b0 + nb) * D;
    float v0 = ld1(sp + e), v1 = ld1(sp + e + 256);
    float s = wredf(v0 + v1);
    if (lane == 0) sRed[w] = s;
    __syncthreads();
    float mu = (sRed[nb*4] + sRed[nb*4+1] + sRed[nb*4+2] + sRed[nb*4+3]) * (1.0f/512.0f);
    __syncthreads();
    float d0 = v0 - mu, d1 = v1 - mu;
    float q = wredf(d0*d0 + d1*d1);
    if (lane == 0) sRed[w] = q;
    __syncthreads();
    float sd = sqrtf((sRed[nb*4] + sRed[nb*4+1] + sRed[nb*4+2] + sRed[nb*4+3]) * (1.0f/512.0f) + 1e-5f);
    dst[nb*512 + e]       = d0 / sd * gamma[e]       + beta[e];
    dst[nb*512 + e + 256] = d1 / sd * gamma[e + 256] + beta[e + 256];
    __syncthreads();
  };

  // ---- initial: embed BOS at position 0 (blocks 0..7 handle batch=bid) ----
  if (bid < BB) {
    float pe = (tid & 1) ? 1.0f : 0.0f;
    st1(&xcur[bid * D + tid], emb[(size_t)BOS_ID * D + tid] * SQD + pe);
  }
  gbarg();

  for (int t = 0; t < STEPS; ++t) {
    const int T = t + 1;
    for (int l = 0; l < NL; ++l) {
      const float* wqkv0 = qkv_w + ((size_t)l * 2 + 0) * (3 * D) * D;
      const float* bqkv0 = qkv_b + ((size_t)l * 2 + 0) * (3 * D);
      const float* wqkv1 = qkv_w + ((size_t)l * 2 + 1) * (3 * D) * D;
      const float* bqkv1 = qkv_b + ((size_t)l * 2 + 1) * (3 * D);
      const float* wo0 = out_w + ((size_t)l * 2 + 0) * D * D;
      const float* bo0 = out_b + ((size_t)l * 2 + 0) * D;
      const float* wo1 = out_w + ((size_t)l * 2 + 1) * D * D;
      const float* bo1 = out_b + ((size_t)l * 2 + 1) * D;

      // ---- P1: x1; per wave: 2 q rows + 4 KV rows (batch wb, group-shared) ----
      if (l == 0) {
        int nb = tid >> 8, e = tid & 255;
        sX1[nb*512 + e]       = ld1(&xcur[(b0 + nb) * D + e]);
        sX1[nb*512 + e + 256] = ld1(&xcur[(b0 + nb) * D + e + 256]);
        __syncthreads();
      } else {
        ln2(xt4, lng + ((size_t)(l - 1) * 3 + 2) * D, lnb + ((size_t)(l - 1) * 3 + 2) * D, sX1);
      }
      {
        const float4* xs4 = (const float4*)(sX1 + wb * 512);
        float4 x0 = xs4[lane], x1v = xs4[lane + 64];
        int jq = sb * 8 + ws * 2;                         // q rows (2)
        int kvb = 512 + sb * 16 + ws * 4;                 // kv rows (4), group-shared
        float4 qa[2], qb[2], wa[4], wbv[4];
#pragma unroll
        for (int r = 0; r < 2; ++r) {
          const float4* w4 = (const float4*)(wqkv0 + (size_t)(jq + r) * D);
          qa[r] = w4[lane]; qb[r] = w4[lane + 64];
        }
#pragma unroll
        for (int r = 0; r < 4; ++r) {
          const float4* w4 = (const float4*)(wqkv0 + (size_t)(kvb + r) * D);
          wa[r] = w4[lane]; wbv[r] = w4[lane + 64];
        }
        float aq[2], ak[4];
#pragma unroll
        for (int r = 0; r < 2; ++r) aq[r] = DOT8(qa[r], qb[r], x0, x1v);
#pragma unroll
        for (int r = 0; r < 4; ++r) ak[r] = DOT8(wa[r], wbv[r], x0, x1v);
#pragma unroll
        for (int o = 32; o; o >>= 1) {
#pragma unroll
          for (int r = 0; r < 2; ++r) aq[r] += __shfl_xor(aq[r], o, 64);
#pragma unroll
          for (int r = 0; r < 4; ++r) ak[r] += __shfl_xor(ak[r], o, 64);
        }
        if (lane == 0) {
#pragma unroll
          for (int r = 0; r < 2; ++r) {
            int j = jq + r;
            st1(&qS[(size_t)(b0 + wb) * D + j], aq[r] + bqkv0[j]);
          }
#pragma unroll
          for (int r = 0; r < 4; ++r) {
            int j = kvb + r;
            float v = ak[r] + bqkv0[j];
            if (j < 1024)
              st1(&Kc[((((size_t)g2 * NL + l) * NB + wb) * TMAX + t) * D + (j - 512)], v);
            else
              st1(&Vc[((((size_t)g2 * NL + l) * NB + wb) * TMAX + t) * D + (j - 1024)], v);
          }
        }
      }
      gbarg();

      // ---- P2: self-attn (redundant per block, group K/V) + Wo0 + res ----
      {
        int nb = tid >> 8, e = tid & 255;
        sQ[nb*512 + e]       = ld1(&qS[(b0 + nb) * D + e]);
        sQ[nb*512 + e + 256] = ld1(&qS[(b0 + nb) * D + e + 256]);
      }
      __syncthreads();
      for (int o = tid; o < NB * NH * TMAX; o += 512) {
        int nb = o / (NH * TMAX), rem = o - nb * (NH * TMAX);
        int h = rem / TMAX, k = rem - h * TMAX;
        if (k < T) {
          const float4* Kr = (const float4*)(Kc + ((((size_t)g2 * NL + l) * NB + nb) * TMAX + k) * D + h * HD);
          const float4* q4 = (const float4*)(sQ + nb * 512 + h * HD);
          float sc = 0.f;
#pragma unroll
          for (int e = 0; e < 16; ++e) {
            float4 a = Kr[e], b2 = q4[e];
            sc += a.x * b2.x + a.y * b2.y + a.z * b2.z + a.w * b2.w;
          }
          sS[nb * 544 + h * TMAX + k] = sc * 0.125f;
        }
      }
      __syncthreads();
      for (int rr = w; rr < 16; rr += 8) {
        int nb = rr >> 3, h = rr & 7;
        float v = (lane < T) ? sS[nb * 544 + h * TMAX + lane] : -INFINITY;
        float m = wredmaxf(v);
        float p = (lane < T) ? expf(v - m) : 0.f;
        float den = wredf(p);
        if (lane < T) sSP[nb * 544 + h * TMAX + lane] = p / den;
      }
      __syncthreads();
      for (int o = tid; o < 1024; o += 512) {
        int nb = o >> 9, dd = o & 511, h = dd >> 6, d3 = dd & 63;
        const float* Vb = Vc + ((((size_t)g2 * NL + l) * NB + nb) * TMAX) * D + h * HD + d3;
        float acc = 0.f;
        for (int k = 0; k < T; ++k) acc += sSP[nb * 544 + h * TMAX + k] * Vb[(size_t)k * D];
        sAO[nb * 512 + dd] = acc;
      }
      __syncthreads();
      {
        int jb = sb * 8 + ws * 2;
        const float4* yN = (const float4*)(sAO + wb * 512);
        float4 y0 = yN[lane], y1 = yN[lane + 64];
        float acc[2];
#pragma unroll
        for (int r = 0; r < 2; ++r) {
          const float4* w4 = (const float4*)(wo0 + (size_t)(jb + r) * D);
          float4 a0 = w4[lane], a1 = w4[lane + 64];
          acc[r] = DOT8(a0, a1, y0, y1);
        }
#pragma unroll
        for (int o = 32; o; o >>= 1) {
#pragma unroll
          for (int r = 0; r < 2; ++r) acc[r] += __shfl_xor(acc[r], o, 64);
        }
        if (lane == 0) {
#pragma unroll
          for (int r = 0; r < 2; ++r) {
            int j = jb + r;
            st1(&xt2[(size_t)(b0 + wb) * D + j], acc[r] + bo0[j] + sX1[wb * 512 + j]);
          }
        }
      }
      gbarg();

      // ---- P3: x2 = LN(xt2); cross-Q 2 rows/wave ----
      ln2(xt2, lng + ((size_t)l * 3 + 0) * D, lnb + ((size_t)l * 3 + 0) * D, sX2);
      {
        int jb = sb * 8 + ws * 2;
        const float4* yN = (const float4*)(sX2 + wb * 512);
        float4 y0 = yN[lane], y1 = yN[lane + 64];
        float acc[2];
#pragma unroll
        for (int r = 0; r < 2; ++r) {
          const float4* w4 = (const float4*)(wqkv1 + (size_t)(jb + r) * D);
          float4 a0 = w4[lane], a1 = w4[lane + 64];
          acc[r] = DOT8(a0, a1, y0, y1);
        }
#pragma unroll
        for (int o = 32; o; o >>= 1) {
#pragma unroll
          for (int r = 0; r < 2; ++r) acc[r] += __shfl_xor(acc[r], o, 64);
        }
        if (lane == 0) {
#pragma unroll
          for (int r = 0; r < 2; ++r) {
            int j = jb + r;
            st1(&q2S[(size_t)(b0 + wb) * D + j], acc[r] + bqkv1[j]);
          }
        }
      }
      gbarg();

      // ---- P4: cross-attn (redundant, cached cK/cV) + Wo1 + res(x2) ----
      {
        int nb = tid >> 8, e = tid & 255;
        sQ[nb*512 + e]       = ld1(&q2S[(b0 + nb) * D + e]);
        sQ[nb*512 + e + 256] = ld1(&q2S[(b0 + nb) * D + e + 256]);
      }
      __syncthreads();
      for (int o = tid; o < 1024; o += 512) {
        int nb = o >> 9, dd = o & 511, h = dd >> 6, k = dd & 63;
        const float4* Kr = (const float4*)(cK + (((size_t)l * BB + b0 + nb) * KC + k) * D + h * HD);
        const float4* q4 = (const float4*)(sQ + nb * 512 + h * HD);
        float sc = 0.f;
#pragma unroll
        for (int e = 0; e < 16; ++e) {
          float4 a = Kr[e], b2 = q4[e];
          sc += a.x * b2.x + a.y * b2.y + a.z * b2.z + a.w * b2.w;
        }
        sS[nb * 512 + dd] = sc * 0.125f;
      }
      __syncthreads();
      for (int rr = w; rr < 16; rr += 8) {
        int nb = rr >> 3, h = rr & 7;
        float v = sS[nb * 512 + h * 64 + lane];
        float m = wredmaxf(v);
        float p = expf(v - m);
        float den = wredf(p);
        sSP[nb * 512 + h * 64 + lane] = p / den;
      }
      __syncthreads();
      for (int o = tid; o < 1024; o += 512) {
        int nb = o >> 9, dd = o & 511, h = dd >> 6, d3 = dd & 63;
        const float* Vb = cV + (((size_t)l * BB + b0 + nb) * KC) * D + h * HD + d3;
        float acc = 0.f;
        for (int k = 0; k < KC; ++k) acc += sSP[nb * 512 + h * 64 + k] * Vb[(size_t)k * D];
        sAO[nb * 512 + dd] = acc;
      }
      __syncthreads();
      {
        int jb = sb * 8 + ws * 2;
        const float4* yN = (const float4*)(sAO + wb * 512);
        float4 y0 = yN[lane], y1 = yN[lane + 64];
        float acc[2];
#pragma unroll
        for (int r = 0; r < 2; ++r) {
          const float4* w4 = (const float4*)(wo1 + (size_t)(jb + r) * D);
          float4 a0 = w4[lane], a1 = w4[lane + 64];
          acc[r] = DOT8(a0, a1, y0, y1);
        }
#pragma unroll
        for (int o = 32; o; o >>= 1) {
#pragma unroll
          for (int r = 0; r < 2; ++r) acc[r] += __shfl_xor(acc[r], o, 64);
        }
        if (lane == 0) {
#pragma unroll
          for (int r = 0; r < 2; ++r) {
            int j = jb + r;
            st1(&xt3[(size_t)(b0 + wb) * D + j], acc[r] + bo1[j] + sX2[wb * 512 + j]);
          }
        }
      }
      gbarg();

      // ---- P5: x3 = LN(xt3) -> sX1; FFN1 8 rows/wave (2 passes of 4) + GELU ----
      ln2(xt3, lng + ((size_t)l * 3 + 1) * D, lnb + ((size_t)l * 3 + 1) * D, sX1);
      {
        const float4* xs4 = (const float4*)(sX1 + wb * 512);
        float4 x0 = xs4[lane], x1v = xs4[lane + 64];
        for (int pass = 0; pass < 2; ++pass) {
          int jb = sb * 32 + ws * 8 + pass * 4;
          float4 wa[4], wbv[4];
#pragma unroll
          for (int r = 0; r < 4; ++r) {
            const float4* w4 = (const float4*)(f_w1 + (size_t)l * DFF * D + (size_t)(jb + r) * D);
            wa[r] = w4[lane]; wbv[r] = w4[lane + 64];
          }
          float acc[4];
#pragma unroll
          for (int r = 0; r < 4; ++r) acc[r] = DOT8(wa[r], wbv[r], x0, x1v);
#pragma unroll
          for (int o = 32; o; o >>= 1) {
#pragma unroll
            for (int r = 0; r < 4; ++r) acc[r] += __shfl_xor(acc[r], o, 64);
          }
          if (lane == 0) {
#pragma unroll
            for (int r = 0; r < 4; ++r) {
              int j = jb + r;
              float v = acc[r] + f_b1[(size_t)l * DFF + j];
              v = v * (erff(v / SQRT2) + 1.0f) / 2.0f;
              st1(&hB[(size_t)(b0 + wb) * DFF + j], v);
            }
          }
        }
      }
      gbarg();

      // ---- P6: FFN2 2 rows/wave (2048-dot) + res(x3) ----
      for (int ii = tid; ii < 2048; ii += 512) {
        int nbb = ii >> 10, ee = (ii & 1023) * 2;
        float2 v = ld2(&hB[(size_t)(b0 + nbb) * DFF + ee]);
        sH[nbb * 2048 + ee] = v.x; sH[nbb * 2048 + ee + 1] = v.y;
      }
      __syncthreads();
      {
        int jb = sb * 8 + ws * 2;
        const float4* hN = (const float4*)(sH + wb * 2048);
        float acc[2];
#pragma unroll
        for (int r = 0; r < 2; ++r) {
          const float4* w4 = (const float4*)(f_w2 + (size_t)l * D * DFF + (size_t)(jb + r) * DFF);
          float a = 0.f;
#pragma unroll
          for (int e = 0; e < 8; ++e) {
            float4 aw0 = w4[lane + e * 64];
            float4 hh0 = hN[lane + e * 64];
            a += aw0.x * hh0.x + aw0.y * hh0.y + aw0.z * hh0.z + aw0.w * hh0.w;
          }
          acc[r] = a;
        }
#pragma unroll
        for (int o = 32; o; o >>= 1) {
#pragma unroll
          for (int r = 0; r < 2; ++r) acc[r] += __shfl_xor(acc[r], o, 64);
        }
        if (lane == 0) {
#pragma unroll
          for (int r = 0; r < 2; ++r) {
            int j = jb + r;
            st1(&xt4[(size_t)(b0 + wb) * D + j], acc[r] + f_b2[(size_t)l * D + j] + sX1[wb * 512 + j]);
          }
        }
      }
      if (l < NL - 1) gbarg(); else gbarall();
    } // l

    // ---- logits: global; xf = LN(xt4) all 8 batches; vocab 125 cols/block ----
    for (int ii = tid; ii < 2048; ii += 512) {
      float2 v = ld2(&xt4[2 * ii]);
      sL[2 * ii] = v.x; sL[2 * ii + 1] = v.y;
    }
    __syncthreads();
    {
      int b = w;   // wave per batch row (8 waves = 8 batches)
      float vals[8]; float s = 0.f;
#pragma unroll
      for (int e = 0; e < 8; ++e) { vals[e] = sL[b * D + lane + e * 64]; s += vals[e]; }
      s = wredf(s);
      float mu = s * (1.0f / 512.0f);
      float q = 0.f;
#pragma unroll
      for (int e = 0; e < 8; ++e) { float d0 = vals[e] - mu; q += d0 * d0; }
      q = wredf(q);
      float sd = sqrtf(q * (1.0f / 512.0f) + 1e-5f);
      const float* ga = lng + 11 * D;
      const float* be = lnb + 11 * D;
#pragma unroll
      for (int e = 0; e < 8; ++e)
        sL[b * D + lane + e * 64] = (vals[e] - mu) / sd * ga[lane + e * 64] + be[lane + e * 64];
    }
    __syncthreads();
    for (int i = w; i < 125; i += 8) {
      int v = i * 256 + bid;
      const float4* er = (const float4*)(emb + (size_t)v * D);
      float4 e0 = er[lane], e1 = er[lane + 64];
      float acc[8];
#pragma unroll
      for (int b = 0; b < 8; b++) {
        const float4* x4 = (const float4*)(sL + b * D);
        float4 x0 = x4[lane], x1v = x4[lane + 64];
        acc[b] = DOT8(e0, e1, x0, x1v);
      }
#pragma unroll
      for (int o = 32; o; o >>= 1) {
#pragma unroll
        for (int b = 0; b < 8; b++) acc[b] += __shfl_xor(acc[b], o, 64);
      }
      if (lane == 0) {
#pragma unroll
        for (int b = 0; b < 8; b++) st1(&lg[(size_t)b * NV + v], acc[b]);
      }
    }
    gbarall();

    // ---- sample (blocks 0..7, block b samples batch b) ----
    if (bid < BB) {
      int b = bid;
      if (tid < 256) histA[tid] = 0u;
      __syncthreads();
      for (int v2 = tid; v2 < NV / 2; v2 += 512) {
        float2 f = ld2(&lg[(size_t)b * NV + 2 * v2]);
        unsigned u0 = monok(f.x), u1 = monok(f.y);
        key16[2 * v2] = (unsigned short)(u0 >> 16);
        key16[2 * v2 + 1] = (unsigned short)(u1 >> 16);
        atomicAdd(&histA[u0 >> 24], 1u);
        atomicAdd(&histA[u1 >> 24], 1u);
      }
      __syncthreads();
      if (tid == 0) {
        unsigned k = KTOP, cum = 0;
        for (int bin = 255; bin >= 0; bin--) {
          cum += histA[bin];
          if (cum >= k) { sMeta[0] = (unsigned)bin; sMeta[1] = k - (cum - histA[bin]); break; }
        }
      }
      __syncthreads();
      unsigned selHi = sMeta[0], rem1 = sMeta[1];
      if (tid < 256) histA[tid] = 0u;
      __syncthreads();
      for (int v = tid; v < NV; v += 512) {
        unsigned k16 = key16[v];
        if ((k16 >> 8) == selHi) atomicAdd(&histA[k16 & 255u], 1u);
      }
      __syncthreads();
      if (tid == 0) {
        unsigned k = rem1, cum = 0;
        for (int bin = 255; bin >= 0; bin--) {
          cum += histA[bin];
          if (cum >= k) { sMeta[2] = (selHi << 8) | (unsigned)bin; sMeta[1] = k - (cum - histA[bin]); break; }
        }
        sMeta[3] = 0u;
      }
      __syncthreads();
      unsigned P16 = sMeta[2], rem2 = sMeta[1];
      for (int v = tid; v < NV; v += 512) {
        if (key16[v] == (unsigned short)P16) {
          unsigned i = atomicAdd(&sMeta[3], 1u);
          if (i < 256) sKeys[i] = monok(ld1(&lg[(size_t)b * NV + v]));
        }
      }
      __syncthreads();
      if (tid == 0) {
        unsigned n = sMeta[3]; if (n > 256) n = 256;
        unsigned thr = 0;
        for (unsigned it = 0; it < rem2; ++it) {
          unsigned bestk = 0; int bj = 0;
          for (unsigned jx = 0; jx < n; jx++)
            if (sKeys[jx] > bestk) { bestk = sKeys[jx]; bj = (int)jx; }
          thr = bestk;
          sKeys[bj] = 0u;
        }
        sMeta[5] = (thr & 0x80000000u) ? (thr ^ 0x80000000u) : ~thr;
      }
      __syncthreads();
      float th = __uint_as_float(sMeta[5]);
      unsigned k0, k1;
      tf2x32(0u, 1u, 0u, (unsigned)t, k0, k1);
      float best = -INFINITY; int bi = NV;
      for (int v = tid; v < NV; v += 512) {
        if (key16[v] >= (unsigned short)P16) {
          float lo = ld1(&lg[(size_t)b * NV + v]);
          if (lo >= th) {
            unsigned o0, o1;
            tf2x32(k0, k1, 0u, (unsigned)(b * NV + v), o0, o1);
            unsigned bits = o0 ^ o1;
            unsigned ub = (bits >> 9) | 0x3f800000u;
            float fu = __uint_as_float(ub) - 1.0f;
            const float TINY = 1.17549435e-38f;
            float u = fu * (1.0f - TINY) + TINY;
            u = fmaxf(TINY, u);
            float gmb = -logf(-logf(u));
            float s = lo + gmb;
            if (s > best || (s == best && v < bi)) { best = s; bi = v; }
          }
        }
      }
      for (int o = 32; o; o >>= 1) {
        float ob = __shfl_xor(best, o, 64); int ox = __shfl_xor(bi, o, 64);
        if (ob > best || (ob == best && ox < bi)) { best = ob; bi = ox; }
      }
      if (lane == 0) { sWin[w] = best; sWix[w] = bi; }
      __syncthreads();
      if (tid == 0) {
        float bb = sWin[0]; int bx = sWix[0];
        for (int i2 = 1; i2 < 8; i2++) {
          if (sWin[i2] > bb || (sWin[i2] == bb && sWix[i2] < bx)) { bb = sWin[i2]; bx = sWix[i2]; }
        }
        int tok = bx;
        if (finished) tok = PAD_ID;
        toks[b * TMAX + t + 1] = tok;
        if (tok == EOS_ID) finished = 1;
        sMeta[4] = (unsigned)tok;
      }
      __syncthreads();
      {
        int tok = (int)sMeta[4];
        float omega = expf(-(float)(tid & ~1) * PEC);
        float val = (float)(t + 1) * omega;
        float pe = (tid & 1) ? cosf(val) : sinf(val);
        st1(&xcur[b * D + tid], emb[(size_t)tok * D + tid] * SQD + pe);
      }
    }
    gbarg();
  } // t
}

// ---------------- host orchestration ----------------
extern "C" void kernel_launch(void* const* d_in, const int* in_sizes, int n_in,
                              void* d_out, int out_size, void* d_ws, size_t ws_size,
                              hipStream_t stream)
{
  const float* state = (const float*)d_in[0];
  const float* emb   = (const float*)d_in[1];
  const float* qkv_w = (const float*)d_in[2];
  const float* qkv_b = (const float*)d_in[3];
  const float* out_w = (const float*)d_in[4];
  const float* out_b = (const float*)d_in[5];
  const float* f_w1  = (const float*)d_in[6];
  const float* f_b1  = (const float*)d_in[7];
  const float* f_w2  = (const float*)d_in[8];
  const float* f_b2  = (const float*)d_in[9];
  const float* lng   = (const float*)d_in[10];
  const float* lnb   = (const float*)d_in[11];

  float* ws = (float*)d_ws;
  float* cK   = ws;                                       // 4*8*64*512
  float* cV   = cK + (size_t)NL * BB * KC * D;
  float* Kc   = cV + (size_t)NL * BB * KC * D;
  float* Vc   = Kc + (size_t)8 * NL * NB * TMAX * D;
  float* qS   = Vc + (size_t)8 * NL * NB * TMAX * D;
  float* q2S  = qS + BB * D;
  float* xt2  = q2S + BB * D;
  float* xt3  = xt2 + BB * D;
  float* xt4  = xt3 + BB * D;
  float* hB   = xt4 + BB * D;                             // 8*2048
  float* xcur = hB + BB * DFF;
  float* lg   = xcur + BB * D;                            // 8*32000
  unsigned* bars = (unsigned*)(lg + (size_t)BB * NV);     // 2048 u32

  int* toks = (int*)d_out;

  init_k<<<1, 256, 0, stream>>>(toks, bars);
  cross_kv_k<<<dim3(NL * KC * 32, BB), 256, 0, stream>>>(state, qkv_w, qkv_b, cK, cV);
  decode_k<<<256, 512, 0, stream>>>(emb, qkv_w, qkv_b, out_w, out_b,
                                    f_w1, f_b1, f_w2, f_b2, lng, lnb,
                                    cK, cV, Kc, Vc, qS, q2S,
                                    xt2, xt3, xt4, hB, xcur, lg, bars, toks);
}